// Round 4
// baseline (95.123 us; speedup 1.0000x reference)
//
#include <hip/hip_runtime.h>
#include <math.h>

#define NM 16   // modes
#define NL 6    // layers
#define NW 15   // beamsplitters per layer
#define S2H 2.0f  // sqrt(2*hbar)

typedef float v4f __attribute__((ext_vector_type(4)));

// ws layout (floats): W[32][16] row-major at [0,512), bias[32] at [512,544)

__global__ __launch_bounds__(640) void cv_precompute(
    const float* __restrict__ disp,   // [2][NL][NM][2]
    const float* __restrict__ sq,     // [2][NL][NM][2]
    const float* __restrict__ bs,     // [2][NL][NW][2]
    float* __restrict__ ws)
{
    __shared__ float dxc[2][NL][NM], dpc[2][NL][NM];
    __shared__ float s00[2][NL][NM], s01[2][NL][NM], s11[2][NL][NM];
    __shared__ float bct[2][NL][NW], bcs[2][NL][NW], bss[2][NL][NW];

    int t = threadIdx.x;
    // Phase 1: parallel transcendental precompute into LDS
    if (t < 192) {
        int c = t / 96, rem = t % 96, l = rem / NM, n = rem % NM;
        float a  = disp[((c*NL + l)*NM + n)*2 + 0];
        float ph = disp[((c*NL + l)*NM + n)*2 + 1];
        dxc[c][l][n] = S2H * a * cosf(ph);
        dpc[c][l][n] = S2H * a * sinf(ph);
    } else if (t < 384) {
        int i = t - 192;
        int c = i / 96, rem = i % 96, l = rem / NM, n = rem % NM;
        float r  = fabsf(sq[((c*NL + l)*NM + n)*2 + 0]);
        float ph = sq[((c*NL + l)*NM + n)*2 + 1];
        float ch = coshf(r), sh = sinhf(r);
        float cp = cosf(ph), sp = sinf(ph);
        s00[c][l][n] = ch - cp*sh;
        s01[c][l][n] = -sp*sh;
        s11[c][l][n] = ch + cp*sh;
    } else if (t < 564) {
        int i = t - 384;
        int c = i / 90, rem = i % 90, l = rem / NW, w = rem % NW;
        float z  = bs[((c*NL + l)*NW + w)*2 + 0];
        float ph = bs[((c*NL + l)*NW + w)*2 + 1];
        float th = 1.0f / (1.0f + expf(-z));
        float ct = cosf(th), st = sinf(th);
        bct[c][l][w] = ct;
        bcs[c][l][w] = cosf(ph) * st;
        bss[c][l][w] = sinf(ph) * st;
    }
    __syncthreads();

    // Phase 2: 34 threads propagate basis vectors (pure FMA chain).
    // col < 16: linear column (no displacement). col == 16: bias (zero input
    // WITH displacement). Affine map F(x)=Mx+c decomposes exactly so.
    if (t >= 34) return;
    int c = t / 17;
    int col = t % 17;
    bool isBias = (col == NM);

    float mx[NM], mp[NM];
    #pragma unroll
    for (int n = 0; n < NM; ++n) { mx[n] = 0.f; mp[n] = 0.f; }
    if (!isBias) mx[col] = S2H;   // mx = S2H * x

    for (int l = 0; l < NL; ++l) {
        if (isBias) {
            #pragma unroll
            for (int n = 0; n < NM; ++n) { mx[n] += dxc[c][l][n]; mp[n] += dpc[c][l][n]; }
        }
        #pragma unroll
        for (int n = 0; n < NM; ++n) {
            float a = s00[c][l][n], b = s01[c][l][n], d = s11[c][l][n];
            float nx  = a*mx[n] + b*mp[n];
            float npp = b*mx[n] + d*mp[n];
            mx[n] = nx; mp[n] = npp;
        }
        #pragma unroll
        for (int w = 0; w < NW; ++w) {
            float ct = bct[c][l][w], cst = bcs[c][l][w], sst = bss[c][l][w];
            float x1 = mx[w], x2 = mx[w+1], p1 = mp[w], p2 = mp[w+1];
            mx[w]   = ct*x1  - cst*x2 - sst*p2;
            mx[w+1] = cst*x1 + ct*x2  - sst*p1;
            mp[w]   = sst*x2 + ct*p1  - cst*p2;
            mp[w+1] = sst*x1 + cst*p1 + ct*p2;
        }
    }

    if (c == 0) {
        if (!isBias) {
            #pragma unroll
            for (int n = 0; n < NM; ++n) ws[n*16 + col] = mx[n];
        } else {
            #pragma unroll
            for (int n = 0; n < NM; ++n) ws[512 + n] = mx[n];
        }
    } else {
        if (!isBias) {
            #pragma unroll
            for (int n = 0; n < NM; ++n) ws[(16 + n)*16 + col] = mp[n];
        } else {
            #pragma unroll
            for (int n = 0; n < NM; ++n) ws[512 + 16 + n] = mp[n];
        }
    }
}

__device__ __forceinline__ v4f dot4x16(const float xr[16],
                                       const float4 w[4][4],
                                       const float bias[4])
{
    float acc[4];
    #pragma unroll
    for (int j = 0; j < 4; ++j) acc[j] = bias[j];
    #pragma unroll
    for (int q = 0; q < 4; ++q) {
        #pragma unroll
        for (int j = 0; j < 4; ++j) {
            acc[j] = fmaf(w[j][q].x, xr[q*4+0], acc[j]);
            acc[j] = fmaf(w[j][q].y, xr[q*4+1], acc[j]);
            acc[j] = fmaf(w[j][q].z, xr[q*4+2], acc[j]);
            acc[j] = fmaf(w[j][q].w, xr[q*4+3], acc[j]);
        }
    }
    v4f r; r[0] = acc[0]; r[1] = acc[1]; r[2] = acc[2]; r[3] = acc[3];
    return r;
}

// Each thread produces float4 output chunks k = b*8 + c (out[b][4c..4c+4)).
// c = threadIdx.x & 7 fixed per thread -> its 4 W rows + bias in registers.
// DEEP MLP: grid sized so each thread handles 4 chunks in ONE straight-line
// pass — all 16 global_load_dwordx4 issued back-to-back (16 outstanding VMEM
// per wave) before any use; then 4 dot+NT-store pairs. No loop-carried
// latency re-pay. Stores lane-consecutive float4 (1 KB/wave), non-temporal.
__global__ __launch_bounds__(256) void cv_apply(
    const float* __restrict__ x,
    const float* __restrict__ ws,
    float* __restrict__ out,
    long long nchunks)                  // B * 8
{
    const int c = threadIdx.x & 7;

    float4 w[4][4];
    float  bias[4];
    #pragma unroll
    for (int j = 0; j < 4; ++j) {
        const int n = c * 4 + j;
        #pragma unroll
        for (int q = 0; q < 4; ++q)
            w[j][q] = ((const float4*)ws)[n * 4 + q];
        bias[j] = ws[512 + n];
    }

    const long long G = (long long)gridDim.x * 256;
    v4f* __restrict__ outv = (v4f*)out;
    long long k = (long long)blockIdx.x * 256 + threadIdx.x;

    // Fast path: 4 chunks, all loads in flight together.
    for (; k + 3 * G < nchunks; k += 4 * G) {
        float xr[4][16];
        #pragma unroll
        for (int i = 0; i < 4; ++i) {
            const float4* xp = (const float4*)(x + ((k + i * G) >> 3) * 16);
            #pragma unroll
            for (int q = 0; q < 4; ++q) {
                float4 v = xp[q];
                xr[i][q*4+0] = v.x; xr[i][q*4+1] = v.y;
                xr[i][q*4+2] = v.z; xr[i][q*4+3] = v.w;
            }
        }
        #pragma unroll
        for (int i = 0; i < 4; ++i)
            __builtin_nontemporal_store(dot4x16(xr[i], w, bias),
                                        outv + (k + i * G));
    }
    // Tail (only when nchunks % (4*G) != 0).
    for (; k < nchunks; k += G) {
        float xr[16];
        const float4* xp = (const float4*)(x + (k >> 3) * 16);
        #pragma unroll
        for (int q = 0; q < 4; ++q) {
            float4 v = xp[q];
            xr[q*4+0] = v.x; xr[q*4+1] = v.y;
            xr[q*4+2] = v.z; xr[q*4+3] = v.w;
        }
        __builtin_nontemporal_store(dot4x16(xr, w, bias), outv + k);
    }
}

extern "C" void kernel_launch(void* const* d_in, const int* in_sizes, int n_in,
                              void* d_out, int out_size, void* d_ws, size_t ws_size,
                              hipStream_t stream) {
    const float* x    = (const float*)d_in[0];
    const float* disp = (const float*)d_in[1];
    const float* sq   = (const float*)d_in[2];
    const float* bs   = (const float*)d_in[3];
    float* ws  = (float*)d_ws;
    float* out = (float*)d_out;

    long long B = in_sizes[0] / NM;
    long long nchunks = B * 8;

    cv_precompute<<<1, 640, 0, stream>>>(disp, sq, bs, ws);

    // Each thread: exactly 4 chunks (straight-line). B=1M -> 8192 blocks.
    long long want = nchunks / (256LL * 4);
    if (want < 1) want = 1;
    int blocks = (int)(want < 16384 ? want : 16384);
    cv_apply<<<blocks, 256, 0, stream>>>(x, ws, out, nchunks);
}

// Round 5
// 66.377 us; speedup vs baseline: 1.4331x; 1.4331x over previous
//
#include <hip/hip_runtime.h>
#include <math.h>

#define NM 16   // modes
#define NL 6    // layers
#define NW 15   // beamsplitters per layer
#define S2H 2.0f  // sqrt(2*hbar)

typedef float v2f __attribute__((ext_vector_type(2)));

// ws layout (floats): W[32][16] row-major at [0,512), bias[32] at [512,544)

__global__ __launch_bounds__(640) void cv_precompute(
    const float* __restrict__ disp,   // [2][NL][NM][2]
    const float* __restrict__ sq,     // [2][NL][NM][2]
    const float* __restrict__ bs,     // [2][NL][NW][2]
    float* __restrict__ ws)
{
    __shared__ float dxc[2][NL][NM], dpc[2][NL][NM];
    __shared__ float s00[2][NL][NM], s01[2][NL][NM], s11[2][NL][NM];
    __shared__ float bct[2][NL][NW], bcs[2][NL][NW], bss[2][NL][NW];

    int t = threadIdx.x;
    // Phase 1: parallel transcendental precompute into LDS
    if (t < 192) {
        int c = t / 96, rem = t % 96, l = rem / NM, n = rem % NM;
        float a  = disp[((c*NL + l)*NM + n)*2 + 0];
        float ph = disp[((c*NL + l)*NM + n)*2 + 1];
        dxc[c][l][n] = S2H * a * cosf(ph);
        dpc[c][l][n] = S2H * a * sinf(ph);
    } else if (t < 384) {
        int i = t - 192;
        int c = i / 96, rem = i % 96, l = rem / NM, n = rem % NM;
        float r  = fabsf(sq[((c*NL + l)*NM + n)*2 + 0]);
        float ph = sq[((c*NL + l)*NM + n)*2 + 1];
        float ch = coshf(r), sh = sinhf(r);
        float cp = cosf(ph), sp = sinf(ph);
        s00[c][l][n] = ch - cp*sh;
        s01[c][l][n] = -sp*sh;
        s11[c][l][n] = ch + cp*sh;
    } else if (t < 564) {
        int i = t - 384;
        int c = i / 90, rem = i % 90, l = rem / NW, w = rem % NW;
        float z  = bs[((c*NL + l)*NW + w)*2 + 0];
        float ph = bs[((c*NL + l)*NW + w)*2 + 1];
        float th = 1.0f / (1.0f + expf(-z));
        float ct = cosf(th), st = sinf(th);
        bct[c][l][w] = ct;
        bcs[c][l][w] = cosf(ph) * st;
        bss[c][l][w] = sinf(ph) * st;
    }
    __syncthreads();

    // Phase 2: 34 threads propagate basis vectors (pure FMA chain).
    // col < 16: linear column (no displacement). col == 16: bias (zero input
    // WITH displacement). Affine map F(x)=Mx+c decomposes exactly so.
    if (t >= 34) return;
    int c = t / 17;
    int col = t % 17;
    bool isBias = (col == NM);

    float mx[NM], mp[NM];
    #pragma unroll
    for (int n = 0; n < NM; ++n) { mx[n] = 0.f; mp[n] = 0.f; }
    if (!isBias) mx[col] = S2H;   // mx = S2H * x

    for (int l = 0; l < NL; ++l) {
        if (isBias) {
            #pragma unroll
            for (int n = 0; n < NM; ++n) { mx[n] += dxc[c][l][n]; mp[n] += dpc[c][l][n]; }
        }
        #pragma unroll
        for (int n = 0; n < NM; ++n) {
            float a = s00[c][l][n], b = s01[c][l][n], d = s11[c][l][n];
            float nx  = a*mx[n] + b*mp[n];
            float npp = b*mx[n] + d*mp[n];
            mx[n] = nx; mp[n] = npp;
        }
        #pragma unroll
        for (int w = 0; w < NW; ++w) {
            float ct = bct[c][l][w], cst = bcs[c][l][w], sst = bss[c][l][w];
            float x1 = mx[w], x2 = mx[w+1], p1 = mp[w], p2 = mp[w+1];
            mx[w]   = ct*x1  - cst*x2 - sst*p2;
            mx[w+1] = cst*x1 + ct*x2  - sst*p1;
            mp[w]   = sst*x2 + ct*p1  - cst*p2;
            mp[w+1] = sst*x1 + cst*p1 + ct*p2;
        }
    }

    if (c == 0) {
        if (!isBias) {
            #pragma unroll
            for (int n = 0; n < NM; ++n) ws[n*16 + col] = mx[n];
        } else {
            #pragma unroll
            for (int n = 0; n < NM; ++n) ws[512 + n] = mx[n];
        }
    } else {
        if (!isBias) {
            #pragma unroll
            for (int n = 0; n < NM; ++n) ws[(16 + n)*16 + col] = mp[n];
        } else {
            #pragma unroll
            for (int n = 0; n < NM; ++n) ws[512 + 16 + n] = mp[n];
        }
    }
}

// Each thread owns TWO output floats: c = tid & 15 -> out rows (2c, 2c+1).
// Per-lane W footprint = 2 rows x 16 floats = 32 VGPR + 2 bias -> genuinely
// register-resident (unlike the 4-row variants, where the compiler reloaded
// W from global every iteration -- the hidden limiter of rounds 1-4).
// Stores: lane-consecutive float2, 512 B/wave contiguous, non-temporal.
// Loads: 16 lanes share a sample; 4 distinct 64 B segments per instruction.
__global__ __launch_bounds__(256) void cv_apply(
    const float* __restrict__ x,
    const float* __restrict__ ws,
    float* __restrict__ out,
    long long ntot)                     // B * 16  (float2 units)
{
    const int c = threadIdx.x & 15;

    // Preload rows 2c, 2c+1 of W and their biases into registers.
    float4 w0[4], w1[4];
    #pragma unroll
    for (int q = 0; q < 4; ++q) {
        w0[q] = ((const float4*)ws)[(2*c + 0) * 4 + q];
        w1[q] = ((const float4*)ws)[(2*c + 1) * 4 + q];
    }
    const float b0 = ws[512 + 2*c + 0];
    const float b1 = ws[512 + 2*c + 1];

    const long long G = (long long)gridDim.x * 256;
    v2f* __restrict__ outv = (v2f*)out;

    for (long long k = (long long)blockIdx.x * 256 + threadIdx.x;
         k < ntot; k += G) {
        const float4* xp = (const float4*)(x + (k >> 4) * 16);
        float4 v0 = xp[0], v1 = xp[1], v2 = xp[2], v3 = xp[3];

        float a0 = b0, a1 = b1;
        a0 = fmaf(w0[0].x, v0.x, a0); a1 = fmaf(w1[0].x, v0.x, a1);
        a0 = fmaf(w0[0].y, v0.y, a0); a1 = fmaf(w1[0].y, v0.y, a1);
        a0 = fmaf(w0[0].z, v0.z, a0); a1 = fmaf(w1[0].z, v0.z, a1);
        a0 = fmaf(w0[0].w, v0.w, a0); a1 = fmaf(w1[0].w, v0.w, a1);
        a0 = fmaf(w0[1].x, v1.x, a0); a1 = fmaf(w1[1].x, v1.x, a1);
        a0 = fmaf(w0[1].y, v1.y, a0); a1 = fmaf(w1[1].y, v1.y, a1);
        a0 = fmaf(w0[1].z, v1.z, a0); a1 = fmaf(w1[1].z, v1.z, a1);
        a0 = fmaf(w0[1].w, v1.w, a0); a1 = fmaf(w1[1].w, v1.w, a1);
        a0 = fmaf(w0[2].x, v2.x, a0); a1 = fmaf(w1[2].x, v2.x, a1);
        a0 = fmaf(w0[2].y, v2.y, a0); a1 = fmaf(w1[2].y, v2.y, a1);
        a0 = fmaf(w0[2].z, v2.z, a0); a1 = fmaf(w1[2].z, v2.z, a1);
        a0 = fmaf(w0[2].w, v2.w, a0); a1 = fmaf(w1[2].w, v2.w, a1);
        a0 = fmaf(w0[3].x, v3.x, a0); a1 = fmaf(w1[3].x, v3.x, a1);
        a0 = fmaf(w0[3].y, v3.y, a0); a1 = fmaf(w1[3].y, v3.y, a1);
        a0 = fmaf(w0[3].z, v3.z, a0); a1 = fmaf(w1[3].z, v3.z, a1);
        a0 = fmaf(w0[3].w, v3.w, a0); a1 = fmaf(w1[3].w, v3.w, a1);

        v2f r; r[0] = a0; r[1] = a1;
        __builtin_nontemporal_store(r, outv + k);
    }
}

extern "C" void kernel_launch(void* const* d_in, const int* in_sizes, int n_in,
                              void* d_out, int out_size, void* d_ws, size_t ws_size,
                              hipStream_t stream) {
    const float* x    = (const float*)d_in[0];
    const float* disp = (const float*)d_in[1];
    const float* sq   = (const float*)d_in[2];
    const float* bs   = (const float*)d_in[3];
    float* ws  = (float*)d_ws;
    float* out = (float*)d_out;

    long long B = in_sizes[0] / NM;
    long long ntot = B * 16;            // float2 output units

    cv_precompute<<<1, 640, 0, stream>>>(disp, sq, bs, ws);

    // 2048 blocks = 8 blocks/CU, ~32 grid-stride iterations/thread.
    long long want = (ntot + 255) / 256;
    int blocks = (int)(want < 2048 ? want : 2048);
    cv_apply<<<blocks, 256, 0, stream>>>(x, ws, out, ntot);
}

// Round 6
// 62.277 us; speedup vs baseline: 1.5274x; 1.0658x over previous
//
#include <hip/hip_runtime.h>
#include <math.h>

#define NM 16   // modes
#define NL 6    // layers
#define NW 15   // beamsplitters per layer
#define S2H 2.0f  // sqrt(2*hbar)

typedef float v4f __attribute__((ext_vector_type(4)));

// ws layout (floats): W[32][16] row-major at [0,512), bias[32] at [512,544)

__global__ __launch_bounds__(640) void cv_precompute(
    const float* __restrict__ disp,   // [2][NL][NM][2]
    const float* __restrict__ sq,     // [2][NL][NM][2]
    const float* __restrict__ bs,     // [2][NL][NW][2]
    float* __restrict__ ws)
{
    __shared__ float dxc[2][NL][NM], dpc[2][NL][NM];
    __shared__ float s00[2][NL][NM], s01[2][NL][NM], s11[2][NL][NM];
    __shared__ float bct[2][NL][NW], bcs[2][NL][NW], bss[2][NL][NW];

    int t = threadIdx.x;
    // Phase 1: parallel transcendental precompute into LDS
    if (t < 192) {
        int c = t / 96, rem = t % 96, l = rem / NM, n = rem % NM;
        float a  = disp[((c*NL + l)*NM + n)*2 + 0];
        float ph = disp[((c*NL + l)*NM + n)*2 + 1];
        dxc[c][l][n] = S2H * a * cosf(ph);
        dpc[c][l][n] = S2H * a * sinf(ph);
    } else if (t < 384) {
        int i = t - 192;
        int c = i / 96, rem = i % 96, l = rem / NM, n = rem % NM;
        float r  = fabsf(sq[((c*NL + l)*NM + n)*2 + 0]);
        float ph = sq[((c*NL + l)*NM + n)*2 + 1];
        float ch = coshf(r), sh = sinhf(r);
        float cp = cosf(ph), sp = sinf(ph);
        s00[c][l][n] = ch - cp*sh;
        s01[c][l][n] = -sp*sh;
        s11[c][l][n] = ch + cp*sh;
    } else if (t < 564) {
        int i = t - 384;
        int c = i / 90, rem = i % 90, l = rem / NW, w = rem % NW;
        float z  = bs[((c*NL + l)*NW + w)*2 + 0];
        float ph = bs[((c*NL + l)*NW + w)*2 + 1];
        float th = 1.0f / (1.0f + expf(-z));
        float ct = cosf(th), st = sinf(th);
        bct[c][l][w] = ct;
        bcs[c][l][w] = cosf(ph) * st;
        bss[c][l][w] = sinf(ph) * st;
    }
    __syncthreads();

    // Phase 2: 34 threads propagate basis vectors (pure FMA chain).
    // col < 16: linear column (no displacement). col == 16: bias (zero input
    // WITH displacement). Affine map F(x)=Mx+c decomposes exactly so.
    if (t >= 34) return;
    int c = t / 17;
    int col = t % 17;
    bool isBias = (col == NM);

    float mx[NM], mp[NM];
    #pragma unroll
    for (int n = 0; n < NM; ++n) { mx[n] = 0.f; mp[n] = 0.f; }
    if (!isBias) mx[col] = S2H;   // mx = S2H * x

    for (int l = 0; l < NL; ++l) {
        if (isBias) {
            #pragma unroll
            for (int n = 0; n < NM; ++n) { mx[n] += dxc[c][l][n]; mp[n] += dpc[c][l][n]; }
        }
        #pragma unroll
        for (int n = 0; n < NM; ++n) {
            float a = s00[c][l][n], b = s01[c][l][n], d = s11[c][l][n];
            float nx  = a*mx[n] + b*mp[n];
            float npp = b*mx[n] + d*mp[n];
            mx[n] = nx; mp[n] = npp;
        }
        #pragma unroll
        for (int w = 0; w < NW; ++w) {
            float ct = bct[c][l][w], cst = bcs[c][l][w], sst = bss[c][l][w];
            float x1 = mx[w], x2 = mx[w+1], p1 = mp[w], p2 = mp[w+1];
            mx[w]   = ct*x1  - cst*x2 - sst*p2;
            mx[w+1] = cst*x1 + ct*x2  - sst*p1;
            mp[w]   = sst*x2 + ct*p1  - cst*p2;
            mp[w+1] = sst*x1 + cst*p1 + ct*p2;
        }
    }

    if (c == 0) {
        if (!isBias) {
            #pragma unroll
            for (int n = 0; n < NM; ++n) ws[n*16 + col] = mx[n];
        } else {
            #pragma unroll
            for (int n = 0; n < NM; ++n) ws[512 + n] = mx[n];
        }
    } else {
        if (!isBias) {
            #pragma unroll
            for (int n = 0; n < NM; ++n) ws[(16 + n)*16 + col] = mp[n];
        } else {
            #pragma unroll
            for (int n = 0; n < NM; ++n) ws[512 + 16 + n] = mp[n];
        }
    }
}

// Each thread produces float4 output chunks k = b*8 + c (out[b][4c..4c+4)).
// c = tid & 7 fixed per thread -> 4 W rows (64 floats) + 4 biases per lane.
// KEY FIX vs rounds 1-5: the W registers are PINNED with an empty
// asm volatile so the AMDGPU scheduler cannot rematerialize the loop-
// invariant W loads inside the loop (it did in every previous round:
// VGPR_Count 52/80/32 < the W footprint each time, i.e. W was silently
// re-fetched from cache every iteration, serializing VMEM behind FMAs).
// __launch_bounds__(256,4) grants a 128-VGPR budget (4 waves/SIMD).
__global__ __launch_bounds__(256, 4) void cv_apply(
    const float* __restrict__ x,
    const float* __restrict__ ws,
    float* __restrict__ out,
    long long nchunks)                  // B * 8
{
    const int c = threadIdx.x & 7;

    // Load rows 4c..4c+3 of W (64 floats) + biases, then pin in VGPRs.
    float wf[4][16];
    float bias[4];
    #pragma unroll
    for (int j = 0; j < 4; ++j) {
        const int n = c * 4 + j;
        #pragma unroll
        for (int q = 0; q < 4; ++q) {
            float4 v = ((const float4*)ws)[n * 4 + q];
            wf[j][q*4+0] = v.x; wf[j][q*4+1] = v.y;
            wf[j][q*4+2] = v.z; wf[j][q*4+3] = v.w;
        }
        bias[j] = ws[512 + n];
    }
    #pragma unroll
    for (int j = 0; j < 4; ++j) {
        asm volatile("" :
            "+v"(wf[j][0]),  "+v"(wf[j][1]),  "+v"(wf[j][2]),  "+v"(wf[j][3]),
            "+v"(wf[j][4]),  "+v"(wf[j][5]),  "+v"(wf[j][6]),  "+v"(wf[j][7]),
            "+v"(wf[j][8]),  "+v"(wf[j][9]),  "+v"(wf[j][10]), "+v"(wf[j][11]),
            "+v"(wf[j][12]), "+v"(wf[j][13]), "+v"(wf[j][14]), "+v"(wf[j][15]));
    }
    asm volatile("" : "+v"(bias[0]), "+v"(bias[1]), "+v"(bias[2]), "+v"(bias[3]));

    const long long G = (long long)gridDim.x * 256;
    v4f* __restrict__ outv = (v4f*)out;

    for (long long k = (long long)blockIdx.x * 256 + threadIdx.x;
         k < nchunks; k += G) {
        const float4* xp = (const float4*)(x + (k >> 3) * 16);
        float xr[16];
        #pragma unroll
        for (int q = 0; q < 4; ++q) {
            float4 v = xp[q];
            xr[q*4+0] = v.x; xr[q*4+1] = v.y;
            xr[q*4+2] = v.z; xr[q*4+3] = v.w;
        }

        float acc[4];
        #pragma unroll
        for (int j = 0; j < 4; ++j) acc[j] = bias[j];
        #pragma unroll
        for (int e = 0; e < 16; ++e) {
            #pragma unroll
            for (int j = 0; j < 4; ++j)
                acc[j] = fmaf(wf[j][e], xr[e], acc[j]);
        }

        v4f r; r[0] = acc[0]; r[1] = acc[1]; r[2] = acc[2]; r[3] = acc[3];
        __builtin_nontemporal_store(r, outv + k);
    }
}

extern "C" void kernel_launch(void* const* d_in, const int* in_sizes, int n_in,
                              void* d_out, int out_size, void* d_ws, size_t ws_size,
                              hipStream_t stream) {
    const float* x    = (const float*)d_in[0];
    const float* disp = (const float*)d_in[1];
    const float* sq   = (const float*)d_in[2];
    const float* bs   = (const float*)d_in[3];
    float* ws  = (float*)d_ws;
    float* out = (float*)d_out;

    long long B = in_sizes[0] / NM;
    long long nchunks = B * 8;          // float4 output units

    cv_precompute<<<1, 640, 0, stream>>>(disp, sq, bs, ws);

    // 2048 blocks = 8 blocks/CU, 16 grid-stride iterations/thread.
    long long want = (nchunks + 255) / 256;
    int blocks = (int)(want < 2048 ? want : 2048);
    cv_apply<<<blocks, 256, 0, stream>>>(x, ws, out, nchunks);
}

// Round 7
// 51.959 us; speedup vs baseline: 1.8307x; 1.1986x over previous
//
#include <hip/hip_runtime.h>
#include <math.h>

#define NM 16   // modes
#define NL 6    // layers
#define NW 15   // beamsplitters per layer
#define S2H 2.0f  // sqrt(2*hbar)
#define BLK 256

typedef float v4f __attribute__((ext_vector_type(4)));

// ws layout (floats): W[32][16] row-major at [0,512), bias[32] at [512,544)

__global__ __launch_bounds__(640) void cv_precompute(
    const float* __restrict__ disp,   // [2][NL][NM][2]
    const float* __restrict__ sq,     // [2][NL][NM][2]
    const float* __restrict__ bs,     // [2][NL][NW][2]
    float* __restrict__ ws)
{
    __shared__ float dxc[2][NL][NM], dpc[2][NL][NM];
    __shared__ float s00[2][NL][NM], s01[2][NL][NM], s11[2][NL][NM];
    __shared__ float bct[2][NL][NW], bcs[2][NL][NW], bss[2][NL][NW];

    int t = threadIdx.x;
    // Phase 1: parallel transcendental precompute into LDS
    if (t < 192) {
        int c = t / 96, rem = t % 96, l = rem / NM, n = rem % NM;
        float a  = disp[((c*NL + l)*NM + n)*2 + 0];
        float ph = disp[((c*NL + l)*NM + n)*2 + 1];
        dxc[c][l][n] = S2H * a * cosf(ph);
        dpc[c][l][n] = S2H * a * sinf(ph);
    } else if (t < 384) {
        int i = t - 192;
        int c = i / 96, rem = i % 96, l = rem / NM, n = rem % NM;
        float r  = fabsf(sq[((c*NL + l)*NM + n)*2 + 0]);
        float ph = sq[((c*NL + l)*NM + n)*2 + 1];
        float ch = coshf(r), sh = sinhf(r);
        float cp = cosf(ph), sp = sinf(ph);
        s00[c][l][n] = ch - cp*sh;
        s01[c][l][n] = -sp*sh;
        s11[c][l][n] = ch + cp*sh;
    } else if (t < 564) {
        int i = t - 384;
        int c = i / 90, rem = i % 90, l = rem / NW, w = rem % NW;
        float z  = bs[((c*NL + l)*NW + w)*2 + 0];
        float ph = bs[((c*NL + l)*NW + w)*2 + 1];
        float th = 1.0f / (1.0f + expf(-z));
        float ct = cosf(th), st = sinf(th);
        bct[c][l][w] = ct;
        bcs[c][l][w] = cosf(ph) * st;
        bss[c][l][w] = sinf(ph) * st;
    }
    __syncthreads();

    // Phase 2: 34 threads propagate basis vectors (pure FMA chain).
    // col < 16: linear column (no displacement). col == 16: bias (zero input
    // WITH displacement). Affine map F(x)=Mx+c decomposes exactly so.
    if (t >= 34) return;
    int c = t / 17;
    int col = t % 17;
    bool isBias = (col == NM);

    float mx[NM], mp[NM];
    #pragma unroll
    for (int n = 0; n < NM; ++n) { mx[n] = 0.f; mp[n] = 0.f; }
    if (!isBias) mx[col] = S2H;   // mx = S2H * x

    for (int l = 0; l < NL; ++l) {
        if (isBias) {
            #pragma unroll
            for (int n = 0; n < NM; ++n) { mx[n] += dxc[c][l][n]; mp[n] += dpc[c][l][n]; }
        }
        #pragma unroll
        for (int n = 0; n < NM; ++n) {
            float a = s00[c][l][n], b = s01[c][l][n], d = s11[c][l][n];
            float nx  = a*mx[n] + b*mp[n];
            float npp = b*mx[n] + d*mp[n];
            mx[n] = nx; mp[n] = npp;
        }
        #pragma unroll
        for (int w = 0; w < NW; ++w) {
            float ct = bct[c][l][w], cst = bcs[c][l][w], sst = bss[c][l][w];
            float x1 = mx[w], x2 = mx[w+1], p1 = mp[w], p2 = mp[w+1];
            mx[w]   = ct*x1  - cst*x2 - sst*p2;
            mx[w+1] = cst*x1 + ct*x2  - sst*p1;
            mp[w]   = sst*x2 + ct*p1  - cst*p2;
            mp[w+1] = sst*x1 + cst*p1 + ct*p2;
        }
    }

    if (c == 0) {
        if (!isBias) {
            #pragma unroll
            for (int n = 0; n < NM; ++n) ws[n*16 + col] = mx[n];
        } else {
            #pragma unroll
            for (int n = 0; n < NM; ++n) ws[512 + n] = mx[n];
        }
    } else {
        if (!isBias) {
            #pragma unroll
            for (int n = 0; n < NM; ++n) ws[(16 + n)*16 + col] = mp[n];
        } else {
            #pragma unroll
            for (int n = 0; n < NM; ++n) ws[512 + 16 + n] = mp[n];
        }
    }
}

// One lane == one sample. W/bias addresses are tid-INDEPENDENT -> the
// compiler's divergence analysis promotes them to s_load (SGPR/scalar
// cache): zero VGPR footprint for W, no per-iteration vector loads of W.
// (Rounds 1-6 all used per-lane W; the compiler refused to keep it
// register-resident and re-fetched it every iteration = latency bound.)
// Each lane computes its sample's 32 outputs; the 256x32 tile is staged in
// XOR-swizzled LDS (bank-conflict-free b128 both directions) and written
// out as lane-consecutive NT dwordx4 (1 KB/wave/instr, 8 deep per lane).
__global__ __launch_bounds__(256, 4) void cv_apply(
    const float* __restrict__ x,
    const float* __restrict__ ws,
    float* __restrict__ out,
    long long B)
{
    __shared__ float4 st[BLK * 8];      // 32 KB tile, XOR-swizzled

    const int t = threadIdx.x;
    const long long b0 = (long long)blockIdx.x * BLK;
    const long long b = b0 + t;
    const bool live = (b < B);

    // ---- my sample -> registers (4x dwordx4) ----
    float xr[16];
    if (live) {
        const float4* xp = (const float4*)(x + b * 16);
        #pragma unroll
        for (int q = 0; q < 4; ++q) {
            float4 v = xp[q];
            xr[q*4+0] = v.x; xr[q*4+1] = v.y;
            xr[q*4+2] = v.z; xr[q*4+3] = v.w;
        }
    } else {
        #pragma unroll
        for (int e = 0; e < 16; ++e) xr[e] = 0.f;
    }

    // ---- 32 outputs, W via scalar (wave-uniform) loads ----
    float acc[32];
    #pragma unroll
    for (int n = 0; n < 32; ++n) {
        float a = ws[512 + n];                    // uniform -> s_load
        #pragma unroll
        for (int e = 0; e < 16; ++e)
            a = fmaf(ws[n * 16 + e], xr[e], a);   // v_fmac with SGPR operand
        acc[n] = a;
    }

    // ---- stage tile in LDS, XOR-swizzled float4 units ----
    #pragma unroll
    for (int j = 0; j < 8; ++j) {
        float4 v = make_float4(acc[j*4+0], acc[j*4+1], acc[j*4+2], acc[j*4+3]);
        st[t * 8 + (j ^ (t & 7))] = v;
    }
    __syncthreads();

    // ---- coalesced NT store: 8 x 1KB-per-wave dwordx4 ----
    v4f* __restrict__ op = (v4f*)(out + b0 * 32);
    const long long umax = (B - b0) * 8;          // float4 units in this tile
    #pragma unroll
    for (int i = 0; i < 8; ++i) {
        int u = i * BLK + t;                      // float4 index in tile
        if (u < umax) {
            int s = u >> 3, j = u & 7;
            float4 v = st[s * 8 + (j ^ (s & 7))];
            v4f r; r[0] = v.x; r[1] = v.y; r[2] = v.z; r[3] = v.w;
            __builtin_nontemporal_store(r, op + u);
        }
    }
}

extern "C" void kernel_launch(void* const* d_in, const int* in_sizes, int n_in,
                              void* d_out, int out_size, void* d_ws, size_t ws_size,
                              hipStream_t stream) {
    const float* x    = (const float*)d_in[0];
    const float* disp = (const float*)d_in[1];
    const float* sq   = (const float*)d_in[2];
    const float* bs   = (const float*)d_in[3];
    float* ws  = (float*)d_ws;
    float* out = (float*)d_out;

    long long B = in_sizes[0] / NM;

    cv_precompute<<<1, 640, 0, stream>>>(disp, sq, bs, ws);

    int blocks = (int)((B + BLK - 1) / BLK);      // 4096 for B=1M
    cv_apply<<<blocks, BLK, 0, stream>>>(x, ws, out, B);
}

// Round 8
// 44.683 us; speedup vs baseline: 2.1288x; 1.1628x over previous
//
#include <hip/hip_runtime.h>
#include <math.h>

#define NM 16   // modes
#define NL 6    // layers
#define NW 15   // beamsplitters per layer
#define S2H 2.0f  // sqrt(2*hbar)

typedef float v4f __attribute__((ext_vector_type(4)));
typedef short bf16x8 __attribute__((ext_vector_type(8)));
typedef float f32x16 __attribute__((ext_vector_type(16)));

// ws layout:
//   ushort bfrag[64][8]  at byte 0      (1 KB)  — MFMA B-fragment of W^T
//   float  bias[32]      at float 256   (byte 1024)

__device__ __forceinline__ unsigned short f2bf(float f) {
    union { float f; unsigned int u; } v; v.f = f;
    unsigned int r = (v.u + 0x7fffu + ((v.u >> 16) & 1u)) >> 16;   // RNE
    return (unsigned short)r;
}

__global__ __launch_bounds__(640) void cv_precompute(
    const float* __restrict__ disp,   // [2][NL][NM][2]
    const float* __restrict__ sq,     // [2][NL][NM][2]
    const float* __restrict__ bs,     // [2][NL][NW][2]
    float* __restrict__ ws)
{
    __shared__ float dxc[2][NL][NM], dpc[2][NL][NM];
    __shared__ float s00[2][NL][NM], s01[2][NL][NM], s11[2][NL][NM];
    __shared__ float bct[2][NL][NW], bcs[2][NL][NW], bss[2][NL][NW];

    int t = threadIdx.x;
    // Phase 1: parallel transcendental precompute into LDS
    if (t < 192) {
        int c = t / 96, rem = t % 96, l = rem / NM, n = rem % NM;
        float a  = disp[((c*NL + l)*NM + n)*2 + 0];
        float ph = disp[((c*NL + l)*NM + n)*2 + 1];
        dxc[c][l][n] = S2H * a * cosf(ph);
        dpc[c][l][n] = S2H * a * sinf(ph);
    } else if (t < 384) {
        int i = t - 192;
        int c = i / 96, rem = i % 96, l = rem / NM, n = rem % NM;
        float r  = fabsf(sq[((c*NL + l)*NM + n)*2 + 0]);
        float ph = sq[((c*NL + l)*NM + n)*2 + 1];
        float ch = coshf(r), sh = sinhf(r);
        float cp = cosf(ph), sp = sinf(ph);
        s00[c][l][n] = ch - cp*sh;
        s01[c][l][n] = -sp*sh;
        s11[c][l][n] = ch + cp*sh;
    } else if (t < 564) {
        int i = t - 384;
        int c = i / 90, rem = i % 90, l = rem / NW, w = rem % NW;
        float z  = bs[((c*NL + l)*NW + w)*2 + 0];
        float ph = bs[((c*NL + l)*NW + w)*2 + 1];
        float th = 1.0f / (1.0f + expf(-z));
        float ct = cosf(th), st = sinf(th);
        bct[c][l][w] = ct;
        bcs[c][l][w] = cosf(ph) * st;
        bss[c][l][w] = sinf(ph) * st;
    }
    __syncthreads();

    // Phase 2: 34 threads propagate basis vectors (pure FMA chain).
    // col < 16: linear column (no displacement). col == 16: bias (zero input
    // WITH displacement). Affine map F(x)=Mx+c decomposes exactly so.
    if (t >= 34) return;
    int c = t / 17;
    int col = t % 17;
    bool isBias = (col == NM);

    float mx[NM], mp[NM];
    #pragma unroll
    for (int n = 0; n < NM; ++n) { mx[n] = 0.f; mp[n] = 0.f; }
    if (!isBias) mx[col] = S2H;   // mx = S2H * x

    for (int l = 0; l < NL; ++l) {
        if (isBias) {
            #pragma unroll
            for (int n = 0; n < NM; ++n) { mx[n] += dxc[c][l][n]; mp[n] += dpc[c][l][n]; }
        }
        #pragma unroll
        for (int n = 0; n < NM; ++n) {
            float a = s00[c][l][n], b = s01[c][l][n], d = s11[c][l][n];
            float nx  = a*mx[n] + b*mp[n];
            float npp = b*mx[n] + d*mp[n];
            mx[n] = nx; mp[n] = npp;
        }
        #pragma unroll
        for (int w = 0; w < NW; ++w) {
            float ct = bct[c][l][w], cst = bcs[c][l][w], sst = bss[c][l][w];
            float x1 = mx[w], x2 = mx[w+1], p1 = mp[w], p2 = mp[w+1];
            mx[w]   = ct*x1  - cst*x2 - sst*p2;
            mx[w+1] = cst*x1 + ct*x2  - sst*p1;
            mp[w]   = sst*x2 + ct*p1  - cst*p2;
            mp[w+1] = sst*x1 + cst*p1 + ct*p2;
        }
    }

    // Emit MFMA B-fragment of W (bf16) + f32 bias.
    // W[row][k]: row = output channel (0-15 from circuit-0 mx, 16-31 from
    // circuit-1 mp), k = input index = this thread's basis column.
    // B-frag layout (32x32x16): lane = col(row of W? no: B[k][n], n=lane&31)
    //   value at lane L, slot j  =  B[k = 8*(L>>5)+j][n = L&31] = W[n][k].
    ushort* bfp  = (ushort*)ws;
    float* biasp = ws + 256;
    if (!isBias) {
        #pragma unroll
        for (int n = 0; n < NM; ++n) {
            int row = 16*c + n;                       // output channel
            float val = (c == 0) ? mx[n] : mp[n];     // W[row][col]
            int lane = row + 32 * (col >> 3);
            int slot = col & 7;
            bfp[lane * 8 + slot] = f2bf(val);
        }
    } else {
        #pragma unroll
        for (int n = 0; n < NM; ++n)
            biasp[16*c + n] = (c == 0) ? mx[n] : mp[n];
    }
}

// MFMA apply: one wave computes 32 samples x 32 outputs with a single
// v_mfma_f32_32x32x16_bf16 (K=16 matches exactly). W is a prebuilt 1 KB
// B-fragment (one dwordx4 per lane, loaded once) — ends the W-residency
// problem of rounds 1-7 (compiler re-fetched W every iteration; scalar-W
// variant stalled on s_load interleave). A-loads are perfectly dense:
// 64 lanes x 32 B = 2 KB contiguous per wave. Output staged in LDS
// (2-way-conflict writes = free) -> lane-consecutive NT dwordx4.
__global__ __launch_bounds__(256) void cv_apply(
    const float* __restrict__ x,
    const float* __restrict__ ws,
    float* __restrict__ out,
    long long B)
{
    __shared__ float st[128 * 32];                  // 16 KB
    const int t = threadIdx.x;
    const int lane = t & 63;
    const int wave = t >> 6;
    const int n = lane & 31;                        // output channel
    const int kg = lane >> 5;                       // k-group (0/1)

    // B-fragment + bias (once per wave)
    const bf16x8 bfrag = *(const bf16x8*)((const ushort*)ws + lane * 8);
    const float  bn    = (ws + 256)[n];

    const long long b0 = (long long)blockIdx.x * 128;   // block sample base
    const long long row = b0 + wave * 32 + n;           // this lane's sample

    // A-fragment: sample row, k = 8*kg .. 8*kg+7, f32 -> bf16
    float xv[8];
    if (row < B) {
        const float4* xp = (const float4*)(x + row * 16 + kg * 8);
        float4 v0 = xp[0], v1 = xp[1];
        xv[0]=v0.x; xv[1]=v0.y; xv[2]=v0.z; xv[3]=v0.w;
        xv[4]=v1.x; xv[5]=v1.y; xv[6]=v1.z; xv[7]=v1.w;
    } else {
        #pragma unroll
        for (int j = 0; j < 8; ++j) xv[j] = 0.f;
    }
    bf16x8 afrag;
    #pragma unroll
    for (int j = 0; j < 8; ++j) afrag[j] = (short)f2bf(xv[j]);

    f32x16 acc = {};
    acc = __builtin_amdgcn_mfma_f32_32x32x16_bf16(afrag, bfrag, acc, 0, 0, 0);

    // Stage D to LDS: lane holds col n, rows m = (r&3)+8*(r>>2)+4*kg (+wave*32)
    #pragma unroll
    for (int r = 0; r < 16; ++r) {
        int m = (r & 3) + 8 * (r >> 2) + 4 * kg;
        st[(wave * 32 + m) * 32 + n] = acc[r] + bn;
    }
    __syncthreads();

    // Coalesced NT store: tile = 128 samples * 32 f32 = 1024 float4
    v4f* __restrict__ op = (v4f*)(out + b0 * 32);
    const long long u4max = (B - b0 < 128 ? B - b0 : 128) * 8;
    const float4* stv = (const float4*)st;
    #pragma unroll
    for (int i = 0; i < 4; ++i) {
        int u = i * 256 + t;
        if (u < u4max) {
            float4 v = stv[u];
            v4f r; r[0]=v.x; r[1]=v.y; r[2]=v.z; r[3]=v.w;
            __builtin_nontemporal_store(r, op + u);
        }
    }
}

extern "C" void kernel_launch(void* const* d_in, const int* in_sizes, int n_in,
                              void* d_out, int out_size, void* d_ws, size_t ws_size,
                              hipStream_t stream) {
    const float* x    = (const float*)d_in[0];
    const float* disp = (const float*)d_in[1];
    const float* sq   = (const float*)d_in[2];
    const float* bs   = (const float*)d_in[3];
    float* ws  = (float*)d_ws;
    float* out = (float*)d_out;

    long long B = in_sizes[0] / NM;

    cv_precompute<<<1, 640, 0, stream>>>(disp, sq, bs, ws);

    int blocks = (int)((B + 127) / 128);          // 8192 for B=1M
    cv_apply<<<blocks, 256, 0, stream>>>(x, ws, out, B);
}

// Round 9
// 44.014 us; speedup vs baseline: 2.1612x; 1.0152x over previous
//
#include <hip/hip_runtime.h>
#include <math.h>

#define NM 16   // modes
#define NL 6    // layers
#define NW 15   // beamsplitters per layer
#define S2H 2.0f  // sqrt(2*hbar)
#define TILES 4  // 128-sample MFMA tiles per block

typedef float v4f __attribute__((ext_vector_type(4)));
typedef short bf16x8 __attribute__((ext_vector_type(8)));
typedef float f32x16 __attribute__((ext_vector_type(16)));

// ws layout:
//   ushort bfrag[64][8]  at byte 0      (1 KB)  — MFMA B-fragment of W^T
//   float  bias[32]      at float 256   (byte 1024)

__device__ __forceinline__ unsigned short f2bf(float f) {
    union { float f; unsigned int u; } v; v.f = f;
    unsigned int r = (v.u + 0x7fffu + ((v.u >> 16) & 1u)) >> 16;   // RNE
    return (unsigned short)r;
}

__global__ __launch_bounds__(640) void cv_precompute(
    const float* __restrict__ disp,   // [2][NL][NM][2]
    const float* __restrict__ sq,     // [2][NL][NM][2]
    const float* __restrict__ bs,     // [2][NL][NW][2]
    float* __restrict__ ws)
{
    __shared__ float dxc[2][NL][NM], dpc[2][NL][NM];
    __shared__ float s00[2][NL][NM], s01[2][NL][NM], s11[2][NL][NM];
    __shared__ float bct[2][NL][NW], bcs[2][NL][NW], bss[2][NL][NW];

    int t = threadIdx.x;
    // Phase 1: parallel transcendental precompute into LDS
    if (t < 192) {
        int c = t / 96, rem = t % 96, l = rem / NM, n = rem % NM;
        float a  = disp[((c*NL + l)*NM + n)*2 + 0];
        float ph = disp[((c*NL + l)*NM + n)*2 + 1];
        dxc[c][l][n] = S2H * a * cosf(ph);
        dpc[c][l][n] = S2H * a * sinf(ph);
    } else if (t < 384) {
        int i = t - 192;
        int c = i / 96, rem = i % 96, l = rem / NM, n = rem % NM;
        float r  = fabsf(sq[((c*NL + l)*NM + n)*2 + 0]);
        float ph = sq[((c*NL + l)*NM + n)*2 + 1];
        float ch = coshf(r), sh = sinhf(r);
        float cp = cosf(ph), sp = sinf(ph);
        s00[c][l][n] = ch - cp*sh;
        s01[c][l][n] = -sp*sh;
        s11[c][l][n] = ch + cp*sh;
    } else if (t < 564) {
        int i = t - 384;
        int c = i / 90, rem = i % 90, l = rem / NW, w = rem % NW;
        float z  = bs[((c*NL + l)*NW + w)*2 + 0];
        float ph = bs[((c*NL + l)*NW + w)*2 + 1];
        float th = 1.0f / (1.0f + expf(-z));
        float ct = cosf(th), st = sinf(th);
        bct[c][l][w] = ct;
        bcs[c][l][w] = cosf(ph) * st;
        bss[c][l][w] = sinf(ph) * st;
    }
    __syncthreads();

    // Phase 2: 34 threads propagate basis vectors (pure FMA chain).
    // col < 16: linear column (no displacement). col == 16: bias (zero input
    // WITH displacement). Affine map F(x)=Mx+c decomposes exactly so.
    if (t >= 34) return;
    int c = t / 17;
    int col = t % 17;
    bool isBias = (col == NM);

    float mx[NM], mp[NM];
    #pragma unroll
    for (int n = 0; n < NM; ++n) { mx[n] = 0.f; mp[n] = 0.f; }
    if (!isBias) mx[col] = S2H;   // mx = S2H * x

    for (int l = 0; l < NL; ++l) {
        if (isBias) {
            #pragma unroll
            for (int n = 0; n < NM; ++n) { mx[n] += dxc[c][l][n]; mp[n] += dpc[c][l][n]; }
        }
        #pragma unroll
        for (int n = 0; n < NM; ++n) {
            float a = s00[c][l][n], b = s01[c][l][n], d = s11[c][l][n];
            float nx  = a*mx[n] + b*mp[n];
            float npp = b*mx[n] + d*mp[n];
            mx[n] = nx; mp[n] = npp;
        }
        #pragma unroll
        for (int w = 0; w < NW; ++w) {
            float ct = bct[c][l][w], cst = bcs[c][l][w], sst = bss[c][l][w];
            float x1 = mx[w], x2 = mx[w+1], p1 = mp[w], p2 = mp[w+1];
            mx[w]   = ct*x1  - cst*x2 - sst*p2;
            mx[w+1] = cst*x1 + ct*x2  - sst*p1;
            mp[w]   = sst*x2 + ct*p1  - cst*p2;
            mp[w+1] = sst*x1 + cst*p1 + ct*p2;
        }
    }

    // Emit MFMA B-fragment of W (bf16) + f32 bias.
    // B-frag (32x32x16): value at lane L, slot j = B[k=8*(L>>5)+j][n=L&31]
    //   = W[n][k];  this thread owns column k=col of W.
    ushort* bfp  = (ushort*)ws;
    float* biasp = ws + 256;
    if (!isBias) {
        #pragma unroll
        for (int n = 0; n < NM; ++n) {
            int row = 16*c + n;                       // output channel
            float val = (c == 0) ? mx[n] : mp[n];     // W[row][col]
            int lane = row + 32 * (col >> 3);
            int slot = col & 7;
            bfp[lane * 8 + slot] = f2bf(val);
        }
    } else {
        #pragma unroll
        for (int n = 0; n < NM; ++n)
            biasp[16*c + n] = (c == 0) ? mx[n] : mp[n];
    }
}

// MFMA apply, 4 tiles (512 samples) per block.
//  - all 8 A-fragment dwordx4 loads issued up-front (deep VMEM queue)
//  - bias folded into the MFMA C operand (acc init = bias[n])
//  - 4 back-to-back v_mfma_f32_32x32x16_bf16 (K=16 exact)
//  - 4 stage+store phases; NT stores queue ~16 deep per thread (barriers
//    wait on lgkmcnt only, not store vmcnt) — fill-kernel-like store stream.
__global__ __launch_bounds__(256, 4) void cv_apply(
    const float* __restrict__ x,
    const float* __restrict__ ws,
    float* __restrict__ out,
    long long B)
{
    __shared__ float st[128 * 32];                  // 16 KB, reused per tile
    const int t = threadIdx.x;
    const int lane = t & 63;
    const int wave = t >> 6;
    const int n = lane & 31;                        // output channel / D col
    const int kg = lane >> 5;                       // k-group (0/1)

    const bf16x8 bfrag = *(const bf16x8*)((const ushort*)ws + lane * 8);
    const float  bn    = (ws + 256)[n];

    const long long base = (long long)blockIdx.x * (128 * TILES);

    // ---- issue ALL A-fragment loads up front (8 dwordx4 per lane) ----
    float4 va[TILES][2];
    #pragma unroll
    for (int tt = 0; tt < TILES; ++tt) {
        const long long row = base + tt * 128 + wave * 32 + n;
        if (row < B) {
            const float4* xp = (const float4*)(x + row * 16 + kg * 8);
            va[tt][0] = xp[0];
            va[tt][1] = xp[1];
        } else {
            va[tt][0] = make_float4(0.f, 0.f, 0.f, 0.f);
            va[tt][1] = make_float4(0.f, 0.f, 0.f, 0.f);
        }
    }

    // ---- convert + MFMA (bias pre-loaded into C) ----
    f32x16 acc[TILES];
    #pragma unroll
    for (int tt = 0; tt < TILES; ++tt) {
        bf16x8 af;
        af[0] = (short)f2bf(va[tt][0].x); af[1] = (short)f2bf(va[tt][0].y);
        af[2] = (short)f2bf(va[tt][0].z); af[3] = (short)f2bf(va[tt][0].w);
        af[4] = (short)f2bf(va[tt][1].x); af[5] = (short)f2bf(va[tt][1].y);
        af[6] = (short)f2bf(va[tt][1].z); af[7] = (short)f2bf(va[tt][1].w);
        f32x16 cin;
        #pragma unroll
        for (int r = 0; r < 16; ++r) cin[r] = bn;
        acc[tt] = __builtin_amdgcn_mfma_f32_32x32x16_bf16(af, bfrag, cin, 0, 0, 0);
    }

    // ---- stage + coalesced NT store, tile by tile ----
    #pragma unroll
    for (int tt = 0; tt < TILES; ++tt) {
        if (tt) __syncthreads();                    // protect st reuse
        #pragma unroll
        for (int r = 0; r < 16; ++r) {
            int m = (r & 3) + 8 * (r >> 2) + 4 * kg;
            st[(wave * 32 + m) * 32 + n] = acc[tt][r];
        }
        __syncthreads();

        const long long tb = base + tt * 128;      // tile sample base
        v4f* __restrict__ op = (v4f*)(out + tb * 32);
        long long rem = B - tb;
        if (rem <= 0) continue;
        const long long u4max = (rem < 128 ? rem : 128) * 8;
        const float4* stv = (const float4*)st;
        #pragma unroll
        for (int i = 0; i < 4; ++i) {
            int u = i * 256 + t;
            if (u < u4max) {
                float4 v = stv[u];
                v4f r; r[0]=v.x; r[1]=v.y; r[2]=v.z; r[3]=v.w;
                __builtin_nontemporal_store(r, op + u);
            }
        }
    }
}

extern "C" void kernel_launch(void* const* d_in, const int* in_sizes, int n_in,
                              void* d_out, int out_size, void* d_ws, size_t ws_size,
                              hipStream_t stream) {
    const float* x    = (const float*)d_in[0];
    const float* disp = (const float*)d_in[1];
    const float* sq   = (const float*)d_in[2];
    const float* bs   = (const float*)d_in[3];
    float* ws  = (float*)d_ws;
    float* out = (float*)d_out;

    long long B = in_sizes[0] / NM;

    cv_precompute<<<1, 640, 0, stream>>>(disp, sq, bs, ws);

    int blocks = (int)((B + 128 * TILES - 1) / (128 * TILES));  // 2048 for B=1M
    cv_apply<<<blocks, 256, 0, stream>>>(x, ws, out, B);
}